// Round 1
// baseline (3015.922 us; speedup 1.0000x reference)
//
#include <hip/hip_runtime.h>
#include <math.h>

#define NEG_SLOPE 0.2f
#define BN_EPS 1e-5f

// ---------------------------------------------------------------------------
// Generic small linear: out[n][o] = b[o] + sum_k in[n][k] * W[o][k]
// Block = 256 threads; NPB = 256/OUT nodes per block. W staged transposed in
// LDS so consecutive o -> consecutive banks (2-way alias at OUT=64 is free).
// ---------------------------------------------------------------------------
template <int IN, int OUT>
__global__ __launch_bounds__(256) void linear_kernel(
    const float* __restrict__ in, const float* __restrict__ W,
    const float* __restrict__ bias, float* __restrict__ out, int rows) {
  constexpr int NPB = 256 / OUT;
  __shared__ float Ws[IN * OUT];        // Ws[k*OUT + o]
  __shared__ float xs[NPB][IN + 1];     // +1 pad
  for (int idx = threadIdx.x; idx < IN * OUT; idx += 256) {
    int o = idx / IN, k = idx % IN;
    Ws[k * OUT + o] = W[idx];
  }
  int node0 = blockIdx.x * NPB;
  for (int idx = threadIdx.x; idx < NPB * IN; idx += 256) {
    int nn = idx / IN, k = idx % IN;
    int n = node0 + nn;
    xs[nn][k] = (n < rows) ? in[n * IN + k] : 0.f;
  }
  __syncthreads();
  int nn = threadIdx.x / OUT;
  int o  = threadIdx.x % OUT;
  int n  = node0 + nn;
  if (n < rows) {
    float acc = bias[o];
#pragma unroll
    for (int k = 0; k < IN; k++) acc += xs[nn][k] * Ws[k * OUT + o];
    out[n * OUT + o] = acc;
  }
}

// ---------------------------------------------------------------------------
// Pass 1: per-edge attention logit + segment max (ordered-uint atomicMax).
// One wave (64 lanes) per edge; lane j owns feature j.
// ---------------------------------------------------------------------------
__global__ __launch_bounds__(256) void edge_alpha_kernel(
    const int* __restrict__ src, const int* __restrict__ dst,
    const float* __restrict__ edge_attr, const float* __restrict__ xl,
    const float* __restrict__ xr, const float* __restrict__ We,
    const float* __restrict__ att, float* __restrict__ alpha,
    unsigned int* __restrict__ amax_enc, int E_) {
  __shared__ float Wes[16 * 64];  // Wes[k*64 + j] = We[j*16 + k]
  __shared__ float atts[64];
  for (int idx = threadIdx.x; idx < 16 * 64; idx += 256) {
    int j = idx / 16, k = idx % 16;
    Wes[k * 64 + j] = We[idx];
  }
  if (threadIdx.x < 64) atts[threadIdx.x] = att[threadIdx.x];
  __syncthreads();
  int e = blockIdx.x * 4 + (threadIdx.x >> 6);
  int j = threadIdx.x & 63;
  if (e >= E_) return;
  int s = src[e], d = dst[e];
  float ea = 0.f;
#pragma unroll
  for (int k = 0; k < 16; k++) ea += edge_attr[e * 16 + k] * Wes[k * 64 + j];
  float m = xl[s * 64 + j] + xr[d * 64 + j] + ea;
  m = (m > 0.f) ? m : NEG_SLOPE * m;
  float v = m * atts[j];
#pragma unroll
  for (int off = 32; off > 0; off >>= 1) v += __shfl_down(v, off);
  if (j == 0) {
    alpha[e] = v;
    unsigned int bits = __float_as_uint(v);
    unsigned int enc = (bits & 0x80000000u) ? ~bits : (bits | 0x80000000u);
    atomicMax(&amax_enc[d], enc);
  }
}

// ---------------------------------------------------------------------------
// Pass 2: ea_exp = exp(alpha - amax[dst]); denom[dst] += ea_exp
// ---------------------------------------------------------------------------
__global__ __launch_bounds__(256) void edge_softmax_kernel(
    const int* __restrict__ dst, const float* __restrict__ alpha,
    const unsigned int* __restrict__ amax_enc, float* __restrict__ ea_exp,
    float* __restrict__ denom, int E_) {
  int e = blockIdx.x * 256 + threadIdx.x;
  if (e >= E_) return;
  int d = dst[e];
  unsigned int enc = amax_enc[d];
  unsigned int bits = (enc & 0x80000000u) ? (enc & 0x7FFFFFFFu) : ~enc;
  float amax = __uint_as_float(bits);
  float ex = expf(alpha[e] - amax);
  ea_exp[e] = ex;
  atomicAdd(&denom[d], ex);
}

// ---------------------------------------------------------------------------
// Pass 3: agg[dst] += (ea_exp/denom[dst]) * xl[src]   (wave per edge)
// ---------------------------------------------------------------------------
__global__ __launch_bounds__(256) void edge_aggregate_kernel(
    const int* __restrict__ src, const int* __restrict__ dst,
    const float* __restrict__ ea_exp, const float* __restrict__ denom,
    const float* __restrict__ xl, float* __restrict__ agg, int E_) {
  int e = blockIdx.x * 4 + (threadIdx.x >> 6);
  int j = threadIdx.x & 63;
  if (e >= E_) return;
  int s = src[e], d = dst[e];
  float w = ea_exp[e] / (denom[d] + 1e-16f);
  atomicAdd(&agg[d * 64 + j], w * xl[s * 64 + j]);
}

// ---------------------------------------------------------------------------
// Node epilogue: conv_bias + BatchNorm(eval) + exact GELU + residual into h
// ---------------------------------------------------------------------------
__global__ __launch_bounds__(256) void node_update_kernel(
    const float* __restrict__ agg, const float* __restrict__ conv_bias,
    const float* __restrict__ gamma, const float* __restrict__ beta,
    const float* __restrict__ mean, const float* __restrict__ var,
    float* __restrict__ h, int total) {
  int idx = blockIdx.x * 256 + threadIdx.x;
  if (idx >= total) return;
  int j = idx & 63;
  float v = agg[idx] + conv_bias[j];
  v = (v - mean[j]) * rsqrtf(var[j] + BN_EPS) * gamma[j] + beta[j];
  float g = 0.5f * v * (1.f + erff(v * 0.70710678118654752f));
  h[idx] += g;
}

// ---------------------------------------------------------------------------
// Final: out128 = h @ lin_W.T + lin_b, atomically pooled per graph.
// Block = 256 = 2 nodes x 128 outputs.
// ---------------------------------------------------------------------------
__global__ __launch_bounds__(256) void lin_pool_kernel(
    const float* __restrict__ h, const float* __restrict__ lin_W,
    const float* __restrict__ lin_b, const int* __restrict__ batch,
    float* __restrict__ pooled, int rows) {
  __shared__ float Ws[64 * 128];     // Ws[k*128 + o]
  __shared__ float xs[2][65];
  for (int idx = threadIdx.x; idx < 64 * 128; idx += 256) {
    int o = idx / 64, k = idx % 64;
    Ws[k * 128 + o] = lin_W[idx];
  }
  int node0 = blockIdx.x * 2;
  for (int idx = threadIdx.x; idx < 2 * 64; idx += 256) {
    int nn = idx / 64, k = idx % 64;
    int n = node0 + nn;
    xs[nn][k] = (n < rows) ? h[n * 64 + k] : 0.f;
  }
  __syncthreads();
  int nn = threadIdx.x >> 7;
  int o  = threadIdx.x & 127;
  int n  = node0 + nn;
  if (n < rows) {
    float acc = lin_b[o];
#pragma unroll
    for (int k = 0; k < 64; k++) acc += xs[nn][k] * Ws[k * 128 + o];
    atomicAdd(&pooled[batch[n] * 128 + o], acc);
  }
}

__global__ __launch_bounds__(256) void counts_kernel(
    const int* __restrict__ batch, float* __restrict__ counts, int rows) {
  int n = blockIdx.x * 256 + threadIdx.x;
  if (n < rows) atomicAdd(&counts[batch[n]], 1.0f);
}

__global__ __launch_bounds__(256) void normalize_kernel(
    float* __restrict__ pooled, const float* __restrict__ counts, int total) {
  int idx = blockIdx.x * 256 + threadIdx.x;
  if (idx < total) pooled[idx] /= fmaxf(counts[idx >> 7], 1.0f);
}

extern "C" void kernel_launch(void* const* d_in, const int* in_sizes, int n_in,
                              void* d_out, int out_size, void* d_ws, size_t ws_size,
                              hipStream_t stream) {
  const float* x         = (const float*)d_in[0];
  const int*   edge_index= (const int*)  d_in[1];
  const float* edge_attr = (const float*)d_in[2];
  const int*   batch     = (const int*)  d_in[3];
  const float* emb_W     = (const float*)d_in[4];
  const float* emb_b     = (const float*)d_in[5];
  const float* Wl        = (const float*)d_in[6];
  const float* bl        = (const float*)d_in[7];
  const float* Wr        = (const float*)d_in[8];
  const float* br        = (const float*)d_in[9];
  const float* We        = (const float*)d_in[10];
  const float* att       = (const float*)d_in[11];
  const float* conv_bias = (const float*)d_in[12];
  const float* bn_gamma  = (const float*)d_in[13];
  const float* bn_beta   = (const float*)d_in[14];
  const float* bn_mean   = (const float*)d_in[15];
  const float* bn_var    = (const float*)d_in[16];
  const float* lin_W     = (const float*)d_in[17];
  const float* lin_b     = (const float*)d_in[18];

  const int N_ = in_sizes[0] / 64;
  const int E_ = in_sizes[1] / 2;
  const int G_ = out_size / 128;
  const int* src = edge_index;
  const int* dst = edge_index + E_;

  // Workspace layout (floats)
  float* ws      = (float*)d_ws;
  float* h       = ws;                 // N*64
  float* xl      = h  + (size_t)N_ * 64;
  float* xr      = xl + (size_t)N_ * 64;
  float* agg     = xr + (size_t)N_ * 64;
  float* alpha   = agg + (size_t)N_ * 64;
  float* ea_exp  = alpha + E_;
  float* denom   = ea_exp + E_;
  unsigned int* amax_enc = (unsigned int*)(denom + N_);
  float* counts  = (float*)(amax_enc + N_);

  // h = x @ emb_W.T + emb_b
  linear_kernel<64, 64><<<(N_ + 3) / 4, 256, 0, stream>>>(x, emb_W, emb_b, h, N_);

  for (int l = 0; l < 3; l++) {
    linear_kernel<64, 64><<<(N_ + 3) / 4, 256, 0, stream>>>(
        h, Wl + (size_t)l * 64 * 64, bl + l * 64, xl, N_);
    linear_kernel<64, 64><<<(N_ + 3) / 4, 256, 0, stream>>>(
        h, Wr + (size_t)l * 64 * 64, br + l * 64, xr, N_);
    hipMemsetAsync(amax_enc, 0, (size_t)N_ * 4, stream);   // enc(0)=-inf stand-in
    hipMemsetAsync(denom, 0, (size_t)N_ * 4, stream);
    hipMemsetAsync(agg, 0, (size_t)N_ * 64 * 4, stream);
    edge_alpha_kernel<<<(E_ + 3) / 4, 256, 0, stream>>>(
        src, dst, edge_attr, xl, xr, We + (size_t)l * 64 * 16, att + l * 64,
        alpha, amax_enc, E_);
    edge_softmax_kernel<<<(E_ + 255) / 256, 256, 0, stream>>>(
        dst, alpha, amax_enc, ea_exp, denom, E_);
    edge_aggregate_kernel<<<(E_ + 3) / 4, 256, 0, stream>>>(
        src, dst, ea_exp, denom, xl, agg, E_);
    node_update_kernel<<<(N_ * 64 + 255) / 256, 256, 0, stream>>>(
        agg, conv_bias + l * 64, bn_gamma + l * 64, bn_beta + l * 64,
        bn_mean + l * 64, bn_var + l * 64, h, N_ * 64);
  }

  hipMemsetAsync(d_out, 0, (size_t)G_ * 128 * 4, stream);
  hipMemsetAsync(counts, 0, (size_t)G_ * 4, stream);
  counts_kernel<<<(N_ + 255) / 256, 256, 0, stream>>>(batch, counts, N_);
  lin_pool_kernel<<<(N_ + 1) / 2, 256, 0, stream>>>(h, lin_W, lin_b, batch,
                                                    (float*)d_out, N_);
  normalize_kernel<<<(G_ * 128 + 255) / 256, 256, 0, stream>>>(
      (float*)d_out, counts, G_ * 128);
}

// Round 2
// 1564.311 us; speedup vs baseline: 1.9280x; 1.9280x over previous
//
#include <hip/hip_runtime.h>
#include <math.h>

#define NEG_SLOPE 0.2f
#define BN_EPS 1e-5f

// ---------------------------------------------------------------------------
// Node linear 64->64: out[n][o] = b[o] + sum_k in[n][k] * W[o][k]
// One block processes 64 nodes; weights staged once, conflict-free.
// Ws[o][k] rows padded to 65 so compute reads (lanes vary o) are 2-way = free.
// ---------------------------------------------------------------------------
__global__ __launch_bounds__(256) void linear64_kernel(
    const float* __restrict__ in, const float* __restrict__ W,
    const float* __restrict__ bias, float* __restrict__ out, int rows) {
  __shared__ float Ws[64][65];
  __shared__ float xs[4][64];
  for (int idx = threadIdx.x; idx < 4096; idx += 256)
    Ws[idx >> 6][idx & 63] = W[idx];           // coalesced read, seq LDS write
  int o = threadIdx.x & 63;
  int slot = threadIdx.x >> 6;                  // 0..3
  float b = bias[o];
  int node0 = blockIdx.x * 64;
  for (int c = 0; c < 64; c += 4) {
    __syncthreads();
    {
      int n = node0 + c + slot;
      xs[slot][o] = (n < rows) ? in[n * 64 + o] : 0.f;
    }
    __syncthreads();
    int n = node0 + c + slot;
    if (n < rows) {
      float acc = b;
#pragma unroll
      for (int k = 0; k < 64; k++) acc += xs[slot][k] * Ws[o][k];
      out[n * 64 + o] = acc;
    }
  }
}

// ---------------------------------------------------------------------------
// Fused xl/xr: two 64->64 linears sharing the input read.
// ---------------------------------------------------------------------------
__global__ __launch_bounds__(256) void linear64x2_kernel(
    const float* __restrict__ in, const float* __restrict__ Wl,
    const float* __restrict__ bl, const float* __restrict__ Wr,
    const float* __restrict__ br, float* __restrict__ xl,
    float* __restrict__ xr, int rows) {
  __shared__ float Wls[64][65];
  __shared__ float Wrs[64][65];
  __shared__ float xs[4][64];
  for (int idx = threadIdx.x; idx < 4096; idx += 256) {
    Wls[idx >> 6][idx & 63] = Wl[idx];
    Wrs[idx >> 6][idx & 63] = Wr[idx];
  }
  int o = threadIdx.x & 63;
  int slot = threadIdx.x >> 6;
  float b0 = bl[o], b1 = br[o];
  int node0 = blockIdx.x * 64;
  for (int c = 0; c < 64; c += 4) {
    __syncthreads();
    {
      int n = node0 + c + slot;
      xs[slot][o] = (n < rows) ? in[n * 64 + o] : 0.f;
    }
    __syncthreads();
    int n = node0 + c + slot;
    if (n < rows) {
      float a0 = b0, a1 = b1;
#pragma unroll
      for (int k = 0; k < 64; k++) {
        float xv = xs[slot][k];
        a0 += xv * Wls[o][k];
        a1 += xv * Wrs[o][k];
      }
      xl[n * 64 + o] = a0;
      xr[n * 64 + o] = a1;
    }
  }
}

// ---------------------------------------------------------------------------
// Pass 1: per-edge attention logit + segment max (ordered-uint atomicMax).
// 64 edges per block (4 waves x 16 iters); lane j owns feature j.
// ---------------------------------------------------------------------------
__global__ __launch_bounds__(256) void edge_alpha_kernel(
    const int* __restrict__ src, const int* __restrict__ dst,
    const float* __restrict__ edge_attr, const float* __restrict__ xl,
    const float* __restrict__ xr, const float* __restrict__ We,
    const float* __restrict__ att, float* __restrict__ alpha,
    unsigned int* __restrict__ amax_enc, int E_) {
  __shared__ float Wes[16][64];  // Wes[k][j] = We[j*16+k]
  __shared__ float atts[64];
  for (int idx = threadIdx.x; idx < 1024; idx += 256) {
    int k = idx >> 6, j = idx & 63;
    Wes[k][j] = We[j * 16 + k];  // seq LDS writes: conflict-free
  }
  if (threadIdx.x < 64) atts[threadIdx.x] = att[threadIdx.x];
  __syncthreads();
  int wave = threadIdx.x >> 6;
  int j = threadIdx.x & 63;
  float aj = atts[j];
  int eend = min(blockIdx.x * 64 + 64, E_);
  for (int e = blockIdx.x * 64 + wave; e < eend; e += 4) {
    int s = src[e], d = dst[e];
    float ea = 0.f;
#pragma unroll
    for (int k = 0; k < 16; k++) ea += edge_attr[e * 16 + k] * Wes[k][j];
    float m = xl[s * 64 + j] + xr[d * 64 + j] + ea;
    m = (m > 0.f) ? m : NEG_SLOPE * m;
    float v = m * aj;
#pragma unroll
    for (int off = 32; off > 0; off >>= 1) v += __shfl_down(v, off);
    if (j == 0) {
      alpha[e] = v;
      unsigned int bits = __float_as_uint(v);
      unsigned int enc = (bits & 0x80000000u) ? ~bits : (bits | 0x80000000u);
      atomicMax(&amax_enc[d], enc);
    }
  }
}

// ---------------------------------------------------------------------------
// Pass 2: ea_exp = exp(alpha - amax[dst]); denom[dst] += ea_exp
// ---------------------------------------------------------------------------
__global__ __launch_bounds__(256) void edge_softmax_kernel(
    const int* __restrict__ dst, const float* __restrict__ alpha,
    const unsigned int* __restrict__ amax_enc, float* __restrict__ ea_exp,
    float* __restrict__ denom, int E_) {
  int e = blockIdx.x * 256 + threadIdx.x;
  if (e >= E_) return;
  int d = dst[e];
  unsigned int enc = amax_enc[d];
  unsigned int bits = (enc & 0x80000000u) ? (enc & 0x7FFFFFFFu) : ~enc;
  float amax = __uint_as_float(bits);
  float ex = expf(alpha[e] - amax);
  ea_exp[e] = ex;
  atomicAdd(&denom[d], ex);
}

// ---------------------------------------------------------------------------
// Pass 3: agg[dst] += (ea_exp/denom[dst]) * xl[src]   (wave per edge, chunked)
// ---------------------------------------------------------------------------
__global__ __launch_bounds__(256) void edge_aggregate_kernel(
    const int* __restrict__ src, const int* __restrict__ dst,
    const float* __restrict__ ea_exp, const float* __restrict__ denom,
    const float* __restrict__ xl, float* __restrict__ agg, int E_) {
  int wave = threadIdx.x >> 6;
  int j = threadIdx.x & 63;
  int eend = min(blockIdx.x * 64 + 64, E_);
  for (int e = blockIdx.x * 64 + wave; e < eend; e += 4) {
    int s = src[e], d = dst[e];
    float w = ea_exp[e] / (denom[d] + 1e-16f);
    atomicAdd(&agg[d * 64 + j], w * xl[s * 64 + j]);
  }
}

// ---------------------------------------------------------------------------
// Node epilogue: conv_bias + BatchNorm(eval) + exact GELU + residual into h
// ---------------------------------------------------------------------------
__global__ __launch_bounds__(256) void node_update_kernel(
    const float* __restrict__ agg, const float* __restrict__ conv_bias,
    const float* __restrict__ gamma, const float* __restrict__ beta,
    const float* __restrict__ mean, const float* __restrict__ var,
    float* __restrict__ h, int total) {
  int idx = blockIdx.x * 256 + threadIdx.x;
  if (idx >= total) return;
  int j = idx & 63;
  float v = agg[idx] + conv_bias[j];
  v = (v - mean[j]) * rsqrtf(var[j] + BN_EPS) * gamma[j] + beta[j];
  float g = 0.5f * v * (1.f + erff(v * 0.70710678118654752f));
  h[idx] += g;
}

// ---------------------------------------------------------------------------
// Final: out128 = h @ lin_W.T + lin_b, pooled per graph.
// 64 nodes per block (2 slots x 128 outputs); batch is SORTED, so pool in
// registers and flush one atomic per graph-change per thread.
// ---------------------------------------------------------------------------
__global__ __launch_bounds__(256) void lin_pool_kernel(
    const float* __restrict__ h, const float* __restrict__ lin_W,
    const float* __restrict__ lin_b, const int* __restrict__ batch,
    float* __restrict__ pooled, int rows) {
  __shared__ float Ws[128][65];
  __shared__ float xs[2][64];
  for (int idx = threadIdx.x; idx < 8192; idx += 256)
    Ws[idx >> 6][idx & 63] = lin_W[idx];
  int slot = threadIdx.x >> 7;  // 0/1
  int o = threadIdx.x & 127;
  float b = lin_b[o];
  int node0 = blockIdx.x * 64;
  float acc = 0.f;
  int curg = -1;
  for (int c = 0; c < 64; c += 2) {
    __syncthreads();
    if (threadIdx.x < 128) {
      int n = node0 + c + (threadIdx.x >> 6);
      xs[threadIdx.x >> 6][threadIdx.x & 63] =
          (n < rows) ? h[n * 64 + (threadIdx.x & 63)] : 0.f;
    }
    __syncthreads();
    int n = node0 + c + slot;
    if (n < rows) {
      float dot = b;
#pragma unroll
      for (int k = 0; k < 64; k++) dot += xs[slot][k] * Ws[o][k];
      int g = batch[n];
      if (g != curg) {
        if (curg >= 0) atomicAdd(&pooled[curg * 128 + o], acc);
        acc = 0.f;
        curg = g;
      }
      acc += dot;
    }
  }
  if (curg >= 0) atomicAdd(&pooled[curg * 128 + o], acc);
}

__global__ __launch_bounds__(256) void counts_kernel(
    const int* __restrict__ batch, float* __restrict__ counts, int rows) {
  int n = blockIdx.x * 256 + threadIdx.x;
  if (n < rows) atomicAdd(&counts[batch[n]], 1.0f);
}

__global__ __launch_bounds__(256) void normalize_kernel(
    float* __restrict__ pooled, const float* __restrict__ counts, int total) {
  int idx = blockIdx.x * 256 + threadIdx.x;
  if (idx < total) pooled[idx] /= fmaxf(counts[idx >> 7], 1.0f);
}

extern "C" void kernel_launch(void* const* d_in, const int* in_sizes, int n_in,
                              void* d_out, int out_size, void* d_ws, size_t ws_size,
                              hipStream_t stream) {
  const float* x         = (const float*)d_in[0];
  const int*   edge_index= (const int*)  d_in[1];
  const float* edge_attr = (const float*)d_in[2];
  const int*   batch     = (const int*)  d_in[3];
  const float* emb_W     = (const float*)d_in[4];
  const float* emb_b     = (const float*)d_in[5];
  const float* Wl        = (const float*)d_in[6];
  const float* bl        = (const float*)d_in[7];
  const float* Wr        = (const float*)d_in[8];
  const float* br        = (const float*)d_in[9];
  const float* We        = (const float*)d_in[10];
  const float* att       = (const float*)d_in[11];
  const float* conv_bias = (const float*)d_in[12];
  const float* bn_gamma  = (const float*)d_in[13];
  const float* bn_beta   = (const float*)d_in[14];
  const float* bn_mean   = (const float*)d_in[15];
  const float* bn_var    = (const float*)d_in[16];
  const float* lin_W     = (const float*)d_in[17];
  const float* lin_b     = (const float*)d_in[18];

  const int N_ = in_sizes[0] / 64;
  const int E_ = in_sizes[1] / 2;
  const int G_ = out_size / 128;
  const int* src = edge_index;
  const int* dst = edge_index + E_;

  // Workspace layout (floats). agg/denom/amax contiguous -> one memset/layer.
  float* ws      = (float*)d_ws;
  float* h       = ws;                          // N*64
  float* xl      = h  + (size_t)N_ * 64;        // N*64
  float* xr      = xl + (size_t)N_ * 64;        // N*64
  float* alpha   = xr + (size_t)N_ * 64;        // E
  float* ea_exp  = alpha + E_;                  // E
  float* agg     = ea_exp + E_;                 // N*64
  float* denom   = agg + (size_t)N_ * 64;       // N
  unsigned int* amax_enc = (unsigned int*)(denom + N_);  // N
  float* counts  = (float*)(amax_enc + N_);     // G

  const int nodeBlocks = (N_ + 63) / 64;
  const int edgeBlocks = (E_ + 63) / 64;

  // h = x @ emb_W.T + emb_b
  linear64_kernel<<<nodeBlocks, 256, 0, stream>>>(x, emb_W, emb_b, h, N_);

  for (int l = 0; l < 3; l++) {
    linear64x2_kernel<<<nodeBlocks, 256, 0, stream>>>(
        h, Wl + (size_t)l * 4096, bl + l * 64, Wr + (size_t)l * 4096,
        br + l * 64, xl, xr, N_);
    hipMemsetAsync(agg, 0, ((size_t)N_ * 64 + 2 * N_) * 4, stream);
    edge_alpha_kernel<<<edgeBlocks, 256, 0, stream>>>(
        src, dst, edge_attr, xl, xr, We + (size_t)l * 1024, att + l * 64,
        alpha, amax_enc, E_);
    edge_softmax_kernel<<<(E_ + 255) / 256, 256, 0, stream>>>(
        dst, alpha, amax_enc, ea_exp, denom, E_);
    edge_aggregate_kernel<<<edgeBlocks, 256, 0, stream>>>(
        src, dst, ea_exp, denom, xl, agg, E_);
    node_update_kernel<<<(N_ * 64 + 255) / 256, 256, 0, stream>>>(
        agg, conv_bias + l * 64, bn_gamma + l * 64, bn_beta + l * 64,
        bn_mean + l * 64, bn_var + l * 64, h, N_ * 64);
  }

  hipMemsetAsync(d_out, 0, (size_t)G_ * 128 * 4, stream);
  hipMemsetAsync(counts, 0, (size_t)G_ * 4, stream);
  counts_kernel<<<(N_ + 255) / 256, 256, 0, stream>>>(batch, counts, N_);
  lin_pool_kernel<<<nodeBlocks, 256, 0, stream>>>(h, lin_W, lin_b, batch,
                                                  (float*)d_out, N_);
  normalize_kernel<<<(G_ * 128 + 255) / 256, 256, 0, stream>>>(
      (float*)d_out, counts, G_ * 128);
}

// Round 3
// 1368.639 us; speedup vs baseline: 2.2036x; 1.1430x over previous
//
#include <hip/hip_runtime.h>
#include <math.h>

#define NEG_SLOPE 0.2f
#define BN_EPS 1e-5f

// ---------------------------------------------------------------------------
// CSR build: deg histogram -> exclusive scan -> scatter (src,eid) by dst.
// ---------------------------------------------------------------------------
__global__ __launch_bounds__(256) void hist_kernel(
    const int* __restrict__ dst, int* __restrict__ deg, int E_) {
  int e = blockIdx.x * 256 + threadIdx.x;
  if (e < E_) atomicAdd(&deg[dst[e]], 1);
}

__global__ __launch_bounds__(256) void scan_kernel(
    const int* __restrict__ deg, int* __restrict__ row_ptr,
    int* __restrict__ cursor, int N_, int E_) {
  __shared__ int partials[256];
  int t = threadIdx.x;
  int slice = (N_ + 255) / 256;
  int s0 = t * slice, s1 = min(s0 + slice, N_);
  int sum = 0;
  for (int i = s0; i < s1; i++) sum += deg[i];
  partials[t] = sum;
  __syncthreads();
  for (int off = 1; off < 256; off <<= 1) {  // Hillis-Steele inclusive
    int v = (t >= off) ? partials[t - off] : 0;
    __syncthreads();
    partials[t] += v;
    __syncthreads();
  }
  int run = (t == 0) ? 0 : partials[t - 1];
  for (int i = s0; i < s1; i++) {
    row_ptr[i] = run;
    cursor[i] = run;
    run += deg[i];
  }
  if (t == 255) row_ptr[N_] = E_;
}

__global__ __launch_bounds__(256) void scatter_kernel(
    const int* __restrict__ src, const int* __restrict__ dst,
    int* __restrict__ cursor, int2* __restrict__ csr_se, int E_) {
  int e = blockIdx.x * 256 + threadIdx.x;
  if (e >= E_) return;
  int pos = atomicAdd(&cursor[dst[e]], 1);
  csr_se[pos] = make_int2(src[e], e);
}

// ---------------------------------------------------------------------------
// Node linear 64->64 (embedding). Weights in LDS, conflict-free staging.
// ---------------------------------------------------------------------------
__global__ __launch_bounds__(256) void linear64_kernel(
    const float* __restrict__ in, const float* __restrict__ W,
    const float* __restrict__ bias, float* __restrict__ out, int rows) {
  __shared__ float Ws[64][65];
  __shared__ float xs[4][64];
  for (int idx = threadIdx.x; idx < 4096; idx += 256)
    Ws[idx >> 6][idx & 63] = W[idx];
  int o = threadIdx.x & 63;
  int slot = threadIdx.x >> 6;
  float b = bias[o];
  int node0 = blockIdx.x * 64;
  for (int c = 0; c < 64; c += 4) {
    __syncthreads();
    {
      int n = node0 + c + slot;
      xs[slot][o] = (n < rows) ? in[n * 64 + o] : 0.f;
    }
    __syncthreads();
    int n = node0 + c + slot;
    if (n < rows) {
      float acc = b;
#pragma unroll
      for (int k = 0; k < 64; k++) acc += xs[slot][k] * Ws[o][k];
      out[n * 64 + o] = acc;
    }
  }
}

// ---------------------------------------------------------------------------
// Fused xl/xr: two 64->64 linears sharing the input read.
// ---------------------------------------------------------------------------
__global__ __launch_bounds__(256) void linear64x2_kernel(
    const float* __restrict__ in, const float* __restrict__ Wl,
    const float* __restrict__ bl, const float* __restrict__ Wr,
    const float* __restrict__ br, float* __restrict__ xl,
    float* __restrict__ xr, int rows) {
  __shared__ float Wls[64][65];
  __shared__ float Wrs[64][65];
  __shared__ float xs[4][64];
  for (int idx = threadIdx.x; idx < 4096; idx += 256) {
    Wls[idx >> 6][idx & 63] = Wl[idx];
    Wrs[idx >> 6][idx & 63] = Wr[idx];
  }
  int o = threadIdx.x & 63;
  int slot = threadIdx.x >> 6;
  float b0 = bl[o], b1 = br[o];
  int node0 = blockIdx.x * 64;
  for (int c = 0; c < 64; c += 4) {
    __syncthreads();
    {
      int n = node0 + c + slot;
      xs[slot][o] = (n < rows) ? in[n * 64 + o] : 0.f;
    }
    __syncthreads();
    int n = node0 + c + slot;
    if (n < rows) {
      float a0 = b0, a1 = b1;
#pragma unroll
      for (int k = 0; k < 64; k++) {
        float xv = xs[slot][k];
        a0 += xv * Wls[o][k];
        a1 += xv * Wrs[o][k];
      }
      xl[n * 64 + o] = a0;
      xr[n * 64 + o] = a1;
    }
  }
}

// ---------------------------------------------------------------------------
// Fused GATv2 layer over CSR: one wave per dst node, online softmax,
// epilogue = conv_bias + BN(eval) + exact GELU + residual into h.
// No LDS, no atomics. Lane j owns feature j.
// ---------------------------------------------------------------------------
__global__ __launch_bounds__(256) void gat_fused_kernel(
    const int2* __restrict__ csr_se, const int* __restrict__ row_ptr,
    const float* __restrict__ edge_attr, const float* __restrict__ xl,
    const float* __restrict__ xr, const float* __restrict__ We,
    const float* __restrict__ att, const float* __restrict__ conv_bias,
    const float* __restrict__ gamma, const float* __restrict__ beta,
    const float* __restrict__ mean, const float* __restrict__ var,
    float* __restrict__ h, int N_) {
  int j = threadIdx.x & 63;
  int gwave = (blockIdx.x * 256 + threadIdx.x) >> 6;
  int nwaves = gridDim.x * 4;
  float Wek[16];
#pragma unroll
  for (int k = 0; k < 16; k++) Wek[k] = We[j * 16 + k];
  float att_j = att[j];
  float cb = conv_bias[j];
  float ga = gamma[j], be = beta[j];
  float rs = rsqrtf(var[j] + BN_EPS);
  float mu = mean[j];
  for (int d = gwave; d < N_; d += nwaves) {
    int beg = row_ptr[d], end = row_ptr[d + 1];
    float xrj = xr[d * 64 + j];
    float m = -INFINITY, l = 0.f, acc = 0.f;
    for (int i = beg; i < end; i++) {
      int2 se = csr_se[i];
      float xlv = xl[(size_t)se.x * 64 + j];
      float av = edge_attr[(size_t)se.y * 16 + (j & 15)];
      float ea = 0.f;
#pragma unroll
      for (int k = 0; k < 16; k++) ea += __shfl(av, k, 16) * Wek[k];
      float mm = xlv + xrj + ea;
      mm = (mm > 0.f) ? mm : NEG_SLOPE * mm;
      float v = mm * att_j;
#pragma unroll
      for (int off = 1; off < 64; off <<= 1) v += __shfl_xor(v, off);
      float newm = fmaxf(m, v);
      float s1 = __expf(m - newm);   // first edge: exp(-inf)=0
      float w = __expf(v - newm);
      l = l * s1 + w;
      acc = acc * s1 + w * xlv;
      m = newm;
    }
    float val = acc / (l + 1e-16f);
    val += cb;
    val = (val - mu) * rs * ga + be;
    float g = 0.5f * val * (1.f + erff(val * 0.70710678118654752f));
    h[d * 64 + j] += g;
  }
}

// ---------------------------------------------------------------------------
// Final: out128 = h @ lin_W.T + lin_b, pooled per graph (batch sorted ->
// register accumulation, one atomic per graph-change per thread).
// ---------------------------------------------------------------------------
__global__ __launch_bounds__(256) void lin_pool_kernel(
    const float* __restrict__ h, const float* __restrict__ lin_W,
    const float* __restrict__ lin_b, const int* __restrict__ batch,
    float* __restrict__ pooled, int rows) {
  __shared__ float Ws[128][65];
  __shared__ float xs[2][64];
  for (int idx = threadIdx.x; idx < 8192; idx += 256)
    Ws[idx >> 6][idx & 63] = lin_W[idx];
  int slot = threadIdx.x >> 7;
  int o = threadIdx.x & 127;
  float b = lin_b[o];
  int node0 = blockIdx.x * 64;
  float acc = 0.f;
  int curg = -1;
  for (int c = 0; c < 64; c += 2) {
    __syncthreads();
    if (threadIdx.x < 128) {
      int n = node0 + c + (threadIdx.x >> 6);
      xs[threadIdx.x >> 6][threadIdx.x & 63] =
          (n < rows) ? h[n * 64 + (threadIdx.x & 63)] : 0.f;
    }
    __syncthreads();
    int n = node0 + c + slot;
    if (n < rows) {
      float dot = b;
#pragma unroll
      for (int k = 0; k < 64; k++) dot += xs[slot][k] * Ws[o][k];
      int g = batch[n];
      if (g != curg) {
        if (curg >= 0) atomicAdd(&pooled[curg * 128 + o], acc);
        acc = 0.f;
        curg = g;
      }
      acc += dot;
    }
  }
  if (curg >= 0) atomicAdd(&pooled[curg * 128 + o], acc);
}

__global__ __launch_bounds__(256) void counts_kernel(
    const int* __restrict__ batch, float* __restrict__ counts, int rows) {
  int n = blockIdx.x * 256 + threadIdx.x;
  if (n < rows) atomicAdd(&counts[batch[n]], 1.0f);
}

__global__ __launch_bounds__(256) void normalize_kernel(
    float* __restrict__ pooled, const float* __restrict__ counts, int total) {
  int idx = blockIdx.x * 256 + threadIdx.x;
  if (idx < total) pooled[idx] /= fmaxf(counts[idx >> 7], 1.0f);
}

extern "C" void kernel_launch(void* const* d_in, const int* in_sizes, int n_in,
                              void* d_out, int out_size, void* d_ws, size_t ws_size,
                              hipStream_t stream) {
  const float* x         = (const float*)d_in[0];
  const int*   edge_index= (const int*)  d_in[1];
  const float* edge_attr = (const float*)d_in[2];
  const int*   batch     = (const int*)  d_in[3];
  const float* emb_W     = (const float*)d_in[4];
  const float* emb_b     = (const float*)d_in[5];
  const float* Wl        = (const float*)d_in[6];
  const float* bl        = (const float*)d_in[7];
  const float* Wr        = (const float*)d_in[8];
  const float* br        = (const float*)d_in[9];
  const float* We        = (const float*)d_in[10];
  const float* att       = (const float*)d_in[11];
  const float* conv_bias = (const float*)d_in[12];
  const float* bn_gamma  = (const float*)d_in[13];
  const float* bn_beta   = (const float*)d_in[14];
  const float* bn_mean   = (const float*)d_in[15];
  const float* bn_var    = (const float*)d_in[16];
  const float* lin_W     = (const float*)d_in[17];
  const float* lin_b     = (const float*)d_in[18];

  const int N_ = in_sizes[0] / 64;
  const int E_ = in_sizes[1] / 2;
  const int G_ = out_size / 128;
  const int* src = edge_index;
  const int* dst = edge_index + E_;

  // Workspace layout (4-byte units), ~45 MB total.
  float* ws      = (float*)d_ws;
  float* h       = ws;                          // N*64
  float* xl      = h  + (size_t)N_ * 64;        // N*64
  float* xr      = xl + (size_t)N_ * 64;        // N*64
  int2*  csr_se  = (int2*)(xr + (size_t)N_ * 64);  // E int2
  int*   row_ptr = (int*)(csr_se + E_);         // N+1
  int*   cursor  = row_ptr + (N_ + 1);          // N
  int*   deg     = cursor + N_;                 // N
  float* counts  = (float*)(deg + N_);          // G

  const int nodeBlocks = (N_ + 63) / 64;
  const int eThreads   = (E_ + 255) / 256;

  // --- CSR build (once per call, reused by all 3 layers) ---
  hipMemsetAsync(deg, 0, (size_t)N_ * 4, stream);
  hist_kernel<<<eThreads, 256, 0, stream>>>(dst, deg, E_);
  scan_kernel<<<1, 256, 0, stream>>>(deg, row_ptr, cursor, N_, E_);
  scatter_kernel<<<eThreads, 256, 0, stream>>>(src, dst, cursor, csr_se, E_);

  // h = x @ emb_W.T + emb_b
  linear64_kernel<<<nodeBlocks, 256, 0, stream>>>(x, emb_W, emb_b, h, N_);

  for (int l = 0; l < 3; l++) {
    linear64x2_kernel<<<nodeBlocks, 256, 0, stream>>>(
        h, Wl + (size_t)l * 4096, bl + l * 64, Wr + (size_t)l * 4096,
        br + l * 64, xl, xr, N_);
    gat_fused_kernel<<<2048, 256, 0, stream>>>(
        csr_se, row_ptr, edge_attr, xl, xr, We + (size_t)l * 1024,
        att + l * 64, conv_bias + l * 64, bn_gamma + l * 64, bn_beta + l * 64,
        bn_mean + l * 64, bn_var + l * 64, h, N_);
  }

  hipMemsetAsync(d_out, 0, (size_t)G_ * 128 * 4, stream);
  hipMemsetAsync(counts, 0, (size_t)G_ * 4, stream);
  counts_kernel<<<(N_ + 255) / 256, 256, 0, stream>>>(batch, counts, N_);
  lin_pool_kernel<<<nodeBlocks, 256, 0, stream>>>(h, lin_W, lin_b, batch,
                                                  (float*)d_out, N_);
  normalize_kernel<<<(G_ * 128 + 255) / 256, 256, 0, stream>>>(
      (float*)d_out, counts, G_ * 128);
}

// Round 4
// 1089.594 us; speedup vs baseline: 2.7679x; 1.2561x over previous
//
#include <hip/hip_runtime.h>
#include <math.h>

#define NEG_SLOPE 0.2f
#define BN_EPS 1e-5f

// ---------------------------------------------------------------------------
// CSR build: deg histogram -> exclusive scan -> scatter (src,eid) by dst.
// ---------------------------------------------------------------------------
__global__ __launch_bounds__(256) void hist_kernel(
    const int* __restrict__ dst, int* __restrict__ deg, int E_) {
  int e = blockIdx.x * 256 + threadIdx.x;
  if (e < E_) atomicAdd(&deg[dst[e]], 1);
}

__global__ __launch_bounds__(256) void scan_kernel(
    const int* __restrict__ deg, int* __restrict__ row_ptr,
    int* __restrict__ cursor, int N_, int E_) {
  __shared__ int partials[256];
  int t = threadIdx.x;
  int slice = (N_ + 255) / 256;
  int s0 = t * slice, s1 = min(s0 + slice, N_);
  int sum = 0;
  for (int i = s0; i < s1; i++) sum += deg[i];
  partials[t] = sum;
  __syncthreads();
  for (int off = 1; off < 256; off <<= 1) {  // Hillis-Steele inclusive
    int v = (t >= off) ? partials[t - off] : 0;
    __syncthreads();
    partials[t] += v;
    __syncthreads();
  }
  int run = (t == 0) ? 0 : partials[t - 1];
  for (int i = s0; i < s1; i++) {
    row_ptr[i] = run;
    cursor[i] = run;
    run += deg[i];
  }
  if (t == 255) row_ptr[N_] = E_;
}

__global__ __launch_bounds__(256) void scatter_kernel(
    const int* __restrict__ src, const int* __restrict__ dst,
    int* __restrict__ cursor, int2* __restrict__ csr_se, int E_) {
  int e = blockIdx.x * 256 + threadIdx.x;
  if (e >= E_) return;
  int pos = atomicAdd(&cursor[dst[e]], 1);
  csr_se[pos] = make_int2(src[e], e);
}

// ---------------------------------------------------------------------------
// Node linear 64->64 (embedding). Weights in LDS, conflict-free staging.
// ---------------------------------------------------------------------------
__global__ __launch_bounds__(256) void linear64_kernel(
    const float* __restrict__ in, const float* __restrict__ W,
    const float* __restrict__ bias, float* __restrict__ out, int rows) {
  __shared__ float Ws[64][65];
  __shared__ float xs[4][64];
  for (int idx = threadIdx.x; idx < 4096; idx += 256)
    Ws[idx >> 6][idx & 63] = W[idx];
  int o = threadIdx.x & 63;
  int slot = threadIdx.x >> 6;
  float b = bias[o];
  int node0 = blockIdx.x * 64;
  for (int c = 0; c < 64; c += 4) {
    __syncthreads();
    {
      int n = node0 + c + slot;
      xs[slot][o] = (n < rows) ? in[n * 64 + o] : 0.f;
    }
    __syncthreads();
    int n = node0 + c + slot;
    if (n < rows) {
      float acc = b;
#pragma unroll
      for (int k = 0; k < 64; k++) acc += xs[slot][k] * Ws[o][k];
      out[n * 64 + o] = acc;
    }
  }
}

// ---------------------------------------------------------------------------
// Fused xl/xr: two 64->64 linears sharing the input read.
// ---------------------------------------------------------------------------
__global__ __launch_bounds__(256) void linear64x2_kernel(
    const float* __restrict__ in, const float* __restrict__ Wl,
    const float* __restrict__ bl, const float* __restrict__ Wr,
    const float* __restrict__ br, float* __restrict__ xl,
    float* __restrict__ xr, int rows) {
  __shared__ float Wls[64][65];
  __shared__ float Wrs[64][65];
  __shared__ float xs[4][64];
  for (int idx = threadIdx.x; idx < 4096; idx += 256) {
    Wls[idx >> 6][idx & 63] = Wl[idx];
    Wrs[idx >> 6][idx & 63] = Wr[idx];
  }
  int o = threadIdx.x & 63;
  int slot = threadIdx.x >> 6;
  float b0 = bl[o], b1 = br[o];
  int node0 = blockIdx.x * 64;
  for (int c = 0; c < 64; c += 4) {
    __syncthreads();
    {
      int n = node0 + c + slot;
      xs[slot][o] = (n < rows) ? in[n * 64 + o] : 0.f;
    }
    __syncthreads();
    int n = node0 + c + slot;
    if (n < rows) {
      float a0 = b0, a1 = b1;
#pragma unroll
      for (int k = 0; k < 64; k++) {
        float xv = xs[slot][k];
        a0 += xv * Wls[o][k];
        a1 += xv * Wrs[o][k];
      }
      xl[n * 64 + o] = a0;
      xr[n * 64 + o] = a1;
    }
  }
}

// ---------------------------------------------------------------------------
// Fused GATv2 layer over CSR: one wave per dst node, chunked online softmax.
// Chunk of 8 edges: independent unrolled gather+logit phase (8 loads in
// flight), one max/rescale per chunk, register-resident accumulation.
// Edge id / src are wave-uniform -> scalarized loads of csr_se & edge_attr.
// Epilogue = conv_bias + BN(eval) + exact GELU + residual into h.
// ---------------------------------------------------------------------------
#define CHUNK 8
__global__ __launch_bounds__(256) void gat_fused_kernel(
    const int2* __restrict__ csr_se, const int* __restrict__ row_ptr,
    const float* __restrict__ edge_attr, const float* __restrict__ xl,
    const float* __restrict__ xr, const float* __restrict__ We,
    const float* __restrict__ att, const float* __restrict__ conv_bias,
    const float* __restrict__ gamma, const float* __restrict__ beta,
    const float* __restrict__ mean, const float* __restrict__ var,
    float* __restrict__ h, int N_) {
  int j = threadIdx.x & 63;
  int gwave = (blockIdx.x * 256 + threadIdx.x) >> 6;
  int nwaves = gridDim.x * 4;
  float Wek[16];
#pragma unroll
  for (int k = 0; k < 16; k++) Wek[k] = We[j * 16 + k];
  float att_j = att[j];
  float cb = conv_bias[j];
  float ga = gamma[j], be = beta[j];
  float rs = rsqrtf(var[j] + BN_EPS);
  float mu = mean[j];
  for (int d = gwave; d < N_; d += nwaves) {
    int beg = __builtin_amdgcn_readfirstlane(row_ptr[d]);
    int end = __builtin_amdgcn_readfirstlane(row_ptr[d + 1]);
    float xrj = xr[(size_t)d * 64 + j];
    float m = -INFINITY, l = 0.f, acc = 0.f;
    for (int base = beg; base < end; base += CHUNK) {
      float v[CHUNK], xlv[CHUNK];
#pragma unroll
      for (int t = 0; t < CHUNK; t++) {
        int i = base + t;
        bool valid = (i < end);
        int ii = valid ? i : beg;
        int s   = __builtin_amdgcn_readfirstlane(csr_se[ii].x);
        int eid = __builtin_amdgcn_readfirstlane(csr_se[ii].y);
        xlv[t] = xl[(size_t)s * 64 + j];
        const float4* ap = (const float4*)(edge_attr + (size_t)eid * 16);
        float4 a0 = ap[0], a1 = ap[1], a2 = ap[2], a3 = ap[3];
        float ea = a0.x * Wek[0]  + a0.y * Wek[1]  + a0.z * Wek[2]  + a0.w * Wek[3]
                 + a1.x * Wek[4]  + a1.y * Wek[5]  + a1.z * Wek[6]  + a1.w * Wek[7]
                 + a2.x * Wek[8]  + a2.y * Wek[9]  + a2.z * Wek[10] + a2.w * Wek[11]
                 + a3.x * Wek[12] + a3.y * Wek[13] + a3.z * Wek[14] + a3.w * Wek[15];
        float z = xlv[t] + xrj + ea;
        z = (z > 0.f) ? z : NEG_SLOPE * z;
        float vv = z * att_j;
#pragma unroll
        for (int off = 32; off > 0; off >>= 1) vv += __shfl_xor(vv, off);
        v[t] = valid ? vv : -INFINITY;
      }
      float mc = v[0];
#pragma unroll
      for (int t = 1; t < CHUNK; t++) mc = fmaxf(mc, v[t]);
      float newm = fmaxf(m, mc);
      float sc = __expf(m - newm);  // first chunk: exp(-inf)=0
      l *= sc;
      acc *= sc;
#pragma unroll
      for (int t = 0; t < CHUNK; t++) {
        float w = __expf(v[t] - newm);  // padded slots: exp(-inf)=0
        l += w;
        acc += w * xlv[t];
      }
      m = newm;
    }
    float val = acc / (l + 1e-16f);
    val += cb;
    val = (val - mu) * rs * ga + be;
    float g = 0.5f * val * (1.f + erff(val * 0.70710678118654752f));
    h[(size_t)d * 64 + j] += g;
  }
}

// ---------------------------------------------------------------------------
// Final: out128 = h @ lin_W.T + lin_b, pooled per graph (batch sorted ->
// register accumulation, one atomic per graph-change per thread).
// ---------------------------------------------------------------------------
__global__ __launch_bounds__(256) void lin_pool_kernel(
    const float* __restrict__ h, const float* __restrict__ lin_W,
    const float* __restrict__ lin_b, const int* __restrict__ batch,
    float* __restrict__ pooled, int rows) {
  __shared__ float Ws[128][65];
  __shared__ float xs[2][64];
  for (int idx = threadIdx.x; idx < 8192; idx += 256)
    Ws[idx >> 6][idx & 63] = lin_W[idx];
  int slot = threadIdx.x >> 7;
  int o = threadIdx.x & 127;
  float b = lin_b[o];
  int node0 = blockIdx.x * 64;
  float acc = 0.f;
  int curg = -1;
  for (int c = 0; c < 64; c += 2) {
    __syncthreads();
    if (threadIdx.x < 128) {
      int n = node0 + c + (threadIdx.x >> 6);
      xs[threadIdx.x >> 6][threadIdx.x & 63] =
          (n < rows) ? h[n * 64 + (threadIdx.x & 63)] : 0.f;
    }
    __syncthreads();
    int n = node0 + c + slot;
    if (n < rows) {
      float dot = b;
#pragma unroll
      for (int k = 0; k < 64; k++) dot += xs[slot][k] * Ws[o][k];
      int g = batch[n];
      if (g != curg) {
        if (curg >= 0) atomicAdd(&pooled[curg * 128 + o], acc);
        acc = 0.f;
        curg = g;
      }
      acc += dot;
    }
  }
  if (curg >= 0) atomicAdd(&pooled[curg * 128 + o], acc);
}

__global__ __launch_bounds__(256) void counts_kernel(
    const int* __restrict__ batch, float* __restrict__ counts, int rows) {
  int n = blockIdx.x * 256 + threadIdx.x;
  if (n < rows) atomicAdd(&counts[batch[n]], 1.0f);
}

__global__ __launch_bounds__(256) void normalize_kernel(
    float* __restrict__ pooled, const float* __restrict__ counts, int total) {
  int idx = blockIdx.x * 256 + threadIdx.x;
  if (idx < total) pooled[idx] /= fmaxf(counts[idx >> 7], 1.0f);
}

extern "C" void kernel_launch(void* const* d_in, const int* in_sizes, int n_in,
                              void* d_out, int out_size, void* d_ws, size_t ws_size,
                              hipStream_t stream) {
  const float* x         = (const float*)d_in[0];
  const int*   edge_index= (const int*)  d_in[1];
  const float* edge_attr = (const float*)d_in[2];
  const int*   batch     = (const int*)  d_in[3];
  const float* emb_W     = (const float*)d_in[4];
  const float* emb_b     = (const float*)d_in[5];
  const float* Wl        = (const float*)d_in[6];
  const float* bl        = (const float*)d_in[7];
  const float* Wr        = (const float*)d_in[8];
  const float* br        = (const float*)d_in[9];
  const float* We        = (const float*)d_in[10];
  const float* att       = (const float*)d_in[11];
  const float* conv_bias = (const float*)d_in[12];
  const float* bn_gamma  = (const float*)d_in[13];
  const float* bn_beta   = (const float*)d_in[14];
  const float* bn_mean   = (const float*)d_in[15];
  const float* bn_var    = (const float*)d_in[16];
  const float* lin_W     = (const float*)d_in[17];
  const float* lin_b     = (const float*)d_in[18];

  const int N_ = in_sizes[0] / 64;
  const int E_ = in_sizes[1] / 2;
  const int G_ = out_size / 128;
  const int* src = edge_index;
  const int* dst = edge_index + E_;

  // Workspace layout (4-byte units), ~45 MB total.
  float* ws      = (float*)d_ws;
  float* h       = ws;                          // N*64
  float* xl      = h  + (size_t)N_ * 64;        // N*64
  float* xr      = xl + (size_t)N_ * 64;        // N*64
  int2*  csr_se  = (int2*)(xr + (size_t)N_ * 64);  // E int2
  int*   row_ptr = (int*)(csr_se + E_);         // N+1
  int*   cursor  = row_ptr + (N_ + 1);          // N
  int*   deg     = cursor + N_;                 // N
  float* counts  = (float*)(deg + N_);          // G

  const int nodeBlocks = (N_ + 63) / 64;
  const int eThreads   = (E_ + 255) / 256;

  // --- CSR build (once per call, reused by all 3 layers) ---
  hipMemsetAsync(deg, 0, (size_t)N_ * 4, stream);
  hist_kernel<<<eThreads, 256, 0, stream>>>(dst, deg, E_);
  scan_kernel<<<1, 256, 0, stream>>>(deg, row_ptr, cursor, N_, E_);
  scatter_kernel<<<eThreads, 256, 0, stream>>>(src, dst, cursor, csr_se, E_);

  // h = x @ emb_W.T + emb_b
  linear64_kernel<<<nodeBlocks, 256, 0, stream>>>(x, emb_W, emb_b, h, N_);

  for (int l = 0; l < 3; l++) {
    linear64x2_kernel<<<nodeBlocks, 256, 0, stream>>>(
        h, Wl + (size_t)l * 4096, bl + l * 64, Wr + (size_t)l * 4096,
        br + l * 64, xl, xr, N_);
    gat_fused_kernel<<<2048, 256, 0, stream>>>(
        csr_se, row_ptr, edge_attr, xl, xr, We + (size_t)l * 1024,
        att + l * 64, conv_bias + l * 64, bn_gamma + l * 64, bn_beta + l * 64,
        bn_mean + l * 64, bn_var + l * 64, h, N_);
  }

  hipMemsetAsync(d_out, 0, (size_t)G_ * 128 * 4, stream);
  hipMemsetAsync(counts, 0, (size_t)G_ * 4, stream);
  counts_kernel<<<(N_ + 255) / 256, 256, 0, stream>>>(batch, counts, N_);
  lin_pool_kernel<<<nodeBlocks, 256, 0, stream>>>(h, lin_W, lin_b, batch,
                                                  (float*)d_out, N_);
  normalize_kernel<<<(G_ * 128 + 255) / 256, 256, 0, stream>>>(
      (float*)d_out, counts, G_ * 128);
}

// Round 5
// 1059.081 us; speedup vs baseline: 2.8477x; 1.0288x over previous
//
#include <hip/hip_runtime.h>
#include <math.h>

#define NEG_SLOPE 0.2f
#define BN_EPS 1e-5f

// ---------------------------------------------------------------------------
// CSR build: deg histogram -> exclusive scan -> scatter src/eid by dst.
// ---------------------------------------------------------------------------
__global__ __launch_bounds__(256) void hist_kernel(
    const int* __restrict__ dst, int* __restrict__ deg, int E_) {
  int e = blockIdx.x * 256 + threadIdx.x;
  if (e < E_) atomicAdd(&deg[dst[e]], 1);
}

__global__ __launch_bounds__(256) void scan_kernel(
    const int* __restrict__ deg, int* __restrict__ row_ptr,
    int* __restrict__ cursor, int N_, int E_) {
  __shared__ int partials[256];
  int t = threadIdx.x;
  int slice = (N_ + 255) / 256;
  int s0 = t * slice, s1 = min(s0 + slice, N_);
  int sum = 0;
  for (int i = s0; i < s1; i++) sum += deg[i];
  partials[t] = sum;
  __syncthreads();
  for (int off = 1; off < 256; off <<= 1) {
    int v = (t >= off) ? partials[t - off] : 0;
    __syncthreads();
    partials[t] += v;
    __syncthreads();
  }
  int run = (t == 0) ? 0 : partials[t - 1];
  for (int i = s0; i < s1; i++) {
    row_ptr[i] = run;
    cursor[i] = run;
    run += deg[i];
  }
  if (t == 255) row_ptr[N_] = E_;
}

__global__ __launch_bounds__(256) void scatter_kernel(
    const int* __restrict__ src, const int* __restrict__ dst,
    int* __restrict__ cursor, int* __restrict__ csr_src,
    int* __restrict__ csr_eid, int E_) {
  int e = blockIdx.x * 256 + threadIdx.x;
  if (e >= E_) return;
  int pos = atomicAdd(&cursor[dst[e]], 1);
  csr_src[pos] = src[e];
  csr_eid[pos] = e;
}

// ---------------------------------------------------------------------------
// Node linear 64->64: W column in registers, wave-uniform broadcast row loads.
// No LDS, no barriers. One wave streams nodes.
// ---------------------------------------------------------------------------
__global__ __launch_bounds__(256) void linear64_kernel(
    const float* __restrict__ in, const float* __restrict__ W,
    const float* __restrict__ bias, float* __restrict__ out, int rows) {
  int o = threadIdx.x & 63;
  float4 Wreg[16];
#pragma unroll
  for (int q = 0; q < 16; q++) Wreg[q] = ((const float4*)(W + o * 64))[q];
  float b = bias[o];
  int gw = (blockIdx.x * 256 + threadIdx.x) >> 6;
  int nw = gridDim.x * 4;
  for (int n = gw; n < rows; n += nw) {
    const float4* xp = (const float4*)(in + n * 64);
    float acc = b;
#pragma unroll
    for (int q = 0; q < 16; q++) {
      float4 xv = xp[q];
      acc += xv.x * Wreg[q].x + xv.y * Wreg[q].y + xv.z * Wreg[q].z +
             xv.w * Wreg[q].w;
    }
    out[n * 64 + o] = acc;
  }
}

// Fused xl/xr version: both weight columns in registers (~128 VGPR), shares
// the node-row loads.
__global__ __launch_bounds__(256) void linear64x2_kernel(
    const float* __restrict__ in, const float* __restrict__ Wl,
    const float* __restrict__ bl, const float* __restrict__ Wr,
    const float* __restrict__ br, float* __restrict__ xl,
    float* __restrict__ xr, int rows) {
  int o = threadIdx.x & 63;
  float4 WL[16], WR[16];
#pragma unroll
  for (int q = 0; q < 16; q++) {
    WL[q] = ((const float4*)(Wl + o * 64))[q];
    WR[q] = ((const float4*)(Wr + o * 64))[q];
  }
  float b0 = bl[o], b1 = br[o];
  int gw = (blockIdx.x * 256 + threadIdx.x) >> 6;
  int nw = gridDim.x * 4;
  for (int n = gw; n < rows; n += nw) {
    const float4* xp = (const float4*)(in + n * 64);
    float a0 = b0, a1 = b1;
#pragma unroll
    for (int q = 0; q < 16; q++) {
      float4 xv = xp[q];
      a0 += xv.x * WL[q].x + xv.y * WL[q].y + xv.z * WL[q].z + xv.w * WL[q].w;
      a1 += xv.x * WR[q].x + xv.y * WR[q].y + xv.z * WR[q].z + xv.w * WR[q].w;
    }
    xl[n * 64 + o] = a0;
    xr[n * 64 + o] = a1;
  }
}

// ---------------------------------------------------------------------------
// Fused GATv2 layer over CSR: one wave per dst node, chunked online softmax.
// Per chunk of 8 edges: scalar s_loads of src/eid (scalar addresses), then
// ONE cooperative coalesced vector-load round staging all 8x16 attr floats
// into per-wave LDS + 8 independent xl gathers (single vm epoch), then
// compute with LDS broadcast reads. ~2 memory epochs/chunk instead of 8.
// Epilogue = conv_bias + BN(eval) + exact GELU + residual into h.
// ---------------------------------------------------------------------------
#define CH 8
__global__ __launch_bounds__(256) void gat_fused_kernel(
    const int* __restrict__ csr_src, const int* __restrict__ csr_eid,
    const int* __restrict__ row_ptr, const float* __restrict__ edge_attr,
    const float* __restrict__ xl, const float* __restrict__ xr,
    const float* __restrict__ We, const float* __restrict__ att,
    const float* __restrict__ conv_bias, const float* __restrict__ gamma,
    const float* __restrict__ beta, const float* __restrict__ mean,
    const float* __restrict__ var, float* __restrict__ h, int N_) {
  __shared__ float attr_s[4][CH * 16];  // per-wave staging, no barriers
  int wv = threadIdx.x >> 6;
  int j = threadIdx.x & 63;
  int gwave = (blockIdx.x * 256 + threadIdx.x) >> 6;
  int nwaves = gridDim.x * 4;
  float Wek[16];
#pragma unroll
  for (int k = 0; k < 16; k++) Wek[k] = We[j * 16 + k];
  float att_j = att[j];
  float cb = conv_bias[j];
  float ga = gamma[j], be = beta[j];
  float rs = rsqrtf(var[j] + BN_EPS);
  float mu = mean[j];
  int t0 = j >> 4, kk = j & 15;
  for (int d = gwave; d < N_; d += nwaves) {
    int beg = __builtin_amdgcn_readfirstlane(row_ptr[d]);
    int end = __builtin_amdgcn_readfirstlane(row_ptr[d + 1]);
    float xrj = xr[d * 64 + j];
    float m = -INFINITY, l = 0.f, acc = 0.f;
    for (int base = beg; base < end; base += CH) {
      // --- scalar index loads (addresses are SGPR-computed -> s_load) ---
      int si[CH], ei[CH];
#pragma unroll
      for (int t = 0; t < CH; t++) {
        int idx = min(base + t, end - 1);
        si[t] = csr_src[idx];
        ei[t] = csr_eid[idx];
      }
      // --- cooperative attr staging: 2 coalesced rounds of 64 lanes ---
      int eidA = (t0 == 0) ? ei[0] : (t0 == 1) ? ei[1] : (t0 == 2) ? ei[2] : ei[3];
      int eidB = (t0 == 0) ? ei[4] : (t0 == 1) ? ei[5] : (t0 == 2) ? ei[6] : ei[7];
      float aA = edge_attr[eidA * 16 + kk];
      float aB = edge_attr[eidB * 16 + kk];
      // --- 8 independent xl gathers ---
      float xlv[CH];
#pragma unroll
      for (int t = 0; t < CH; t++) xlv[t] = xl[si[t] * 64 + j];
      attr_s[wv][j] = aA;
      attr_s[wv][64 + j] = aB;
      // --- compute (attrs via LDS broadcast reads) ---
      float v[CH];
#pragma unroll
      for (int t = 0; t < CH; t++) {
        const float4* Ap = (const float4*)&attr_s[wv][t * 16];
        float4 a0 = Ap[0], a1 = Ap[1], a2 = Ap[2], a3 = Ap[3];
        float ea = a0.x * Wek[0]  + a0.y * Wek[1]  + a0.z * Wek[2]  + a0.w * Wek[3]
                 + a1.x * Wek[4]  + a1.y * Wek[5]  + a1.z * Wek[6]  + a1.w * Wek[7]
                 + a2.x * Wek[8]  + a2.y * Wek[9]  + a2.z * Wek[10] + a2.w * Wek[11]
                 + a3.x * Wek[12] + a3.y * Wek[13] + a3.z * Wek[14] + a3.w * Wek[15];
        float z = xlv[t] + xrj + ea;
        z = (z > 0.f) ? z : NEG_SLOPE * z;
        float vv = z * att_j;
#pragma unroll
        for (int off = 32; off > 0; off >>= 1) vv += __shfl_xor(vv, off);
        v[t] = (base + t < end) ? vv : -INFINITY;
      }
      float mc = v[0];
#pragma unroll
      for (int t = 1; t < CH; t++) mc = fmaxf(mc, v[t]);
      float newm = fmaxf(m, mc);
      float sc = __expf(m - newm);  // first chunk: exp(-inf)=0
      l *= sc;
      acc *= sc;
#pragma unroll
      for (int t = 0; t < CH; t++) {
        float w = __expf(v[t] - newm);  // padded slots: exp(-inf)=0
        l += w;
        acc += w * xlv[t];
      }
      m = newm;
    }
    float val = acc / (l + 1e-16f);
    val += cb;
    val = (val - mu) * rs * ga + be;
    float g = 0.5f * val * (1.f + erff(val * 0.70710678118654752f));
    h[d * 64 + j] += g;
  }
}

// ---------------------------------------------------------------------------
// Final: out128 = h @ lin_W.T + lin_b, pooled per graph. W rows in registers,
// wave-uniform broadcast loads of h rows; batch sorted -> register pooling.
// ---------------------------------------------------------------------------
__global__ __launch_bounds__(256) void lin_pool_kernel(
    const float* __restrict__ h, const float* __restrict__ lin_W,
    const float* __restrict__ lin_b, const int* __restrict__ batch,
    float* __restrict__ pooled, int rows) {
  int o = threadIdx.x & 127;
  int slot = threadIdx.x >> 7;
  float4 Wreg[16];
#pragma unroll
  for (int q = 0; q < 16; q++) Wreg[q] = ((const float4*)(lin_W + o * 64))[q];
  float b = lin_b[o];
  int node0 = blockIdx.x * 64;
  float acc = 0.f;
  int curg = -1;
  for (int c = slot; c < 64; c += 2) {
    int n = node0 + c;
    if (n >= rows) break;
    const float4* hp = (const float4*)(h + n * 64);
    float dot = b;
#pragma unroll
    for (int q = 0; q < 16; q++) {
      float4 xv = hp[q];
      dot += xv.x * Wreg[q].x + xv.y * Wreg[q].y + xv.z * Wreg[q].z +
             xv.w * Wreg[q].w;
    }
    int g = batch[n];
    if (g != curg) {
      if (curg >= 0) atomicAdd(&pooled[curg * 128 + o], acc);
      acc = 0.f;
      curg = g;
    }
    acc += dot;
  }
  if (curg >= 0) atomicAdd(&pooled[curg * 128 + o], acc);
}

__global__ __launch_bounds__(256) void counts_kernel(
    const int* __restrict__ batch, float* __restrict__ counts, int rows) {
  int n = blockIdx.x * 256 + threadIdx.x;
  if (n < rows) atomicAdd(&counts[batch[n]], 1.0f);
}

__global__ __launch_bounds__(256) void normalize_kernel(
    float* __restrict__ pooled, const float* __restrict__ counts, int total) {
  int idx = blockIdx.x * 256 + threadIdx.x;
  if (idx < total) pooled[idx] /= fmaxf(counts[idx >> 7], 1.0f);
}

extern "C" void kernel_launch(void* const* d_in, const int* in_sizes, int n_in,
                              void* d_out, int out_size, void* d_ws, size_t ws_size,
                              hipStream_t stream) {
  const float* x         = (const float*)d_in[0];
  const int*   edge_index= (const int*)  d_in[1];
  const float* edge_attr = (const float*)d_in[2];
  const int*   batch     = (const int*)  d_in[3];
  const float* emb_W     = (const float*)d_in[4];
  const float* emb_b     = (const float*)d_in[5];
  const float* Wl        = (const float*)d_in[6];
  const float* bl        = (const float*)d_in[7];
  const float* Wr        = (const float*)d_in[8];
  const float* br        = (const float*)d_in[9];
  const float* We        = (const float*)d_in[10];
  const float* att       = (const float*)d_in[11];
  const float* conv_bias = (const float*)d_in[12];
  const float* bn_gamma  = (const float*)d_in[13];
  const float* bn_beta   = (const float*)d_in[14];
  const float* bn_mean   = (const float*)d_in[15];
  const float* bn_var    = (const float*)d_in[16];
  const float* lin_W     = (const float*)d_in[17];
  const float* lin_b     = (const float*)d_in[18];

  const int N_ = in_sizes[0] / 64;
  const int E_ = in_sizes[1] / 2;
  const int G_ = out_size / 128;
  const int* src = edge_index;
  const int* dst = edge_index + E_;

  // Workspace layout (4-byte units), ~46 MB total.
  float* ws      = (float*)d_ws;
  float* h       = ws;                          // N*64
  float* xl      = h  + (size_t)N_ * 64;        // N*64
  float* xr      = xl + (size_t)N_ * 64;        // N*64
  int*   csr_src = (int*)(xr + (size_t)N_ * 64);// E+8 (slack for clamped tail)
  int*   csr_eid = csr_src + (E_ + 8);          // E+8
  int*   row_ptr = csr_eid + (E_ + 8);          // N+1
  int*   cursor  = row_ptr + (N_ + 1);          // N
  int*   deg     = cursor + N_;                 // N
  float* counts  = (float*)(deg + N_);          // G

  const int eThreads = (E_ + 255) / 256;

  // --- CSR build (once per call, reused by all 3 layers) ---
  hipMemsetAsync(deg, 0, (size_t)N_ * 4, stream);
  hist_kernel<<<eThreads, 256, 0, stream>>>(dst, deg, E_);
  scan_kernel<<<1, 256, 0, stream>>>(deg, row_ptr, cursor, N_, E_);
  scatter_kernel<<<eThreads, 256, 0, stream>>>(src, dst, cursor, csr_src,
                                               csr_eid, E_);

  // h = x @ emb_W.T + emb_b
  linear64_kernel<<<1024, 256, 0, stream>>>(x, emb_W, emb_b, h, N_);

  for (int l = 0; l < 3; l++) {
    linear64x2_kernel<<<1024, 256, 0, stream>>>(
        h, Wl + (size_t)l * 4096, bl + l * 64, Wr + (size_t)l * 4096,
        br + l * 64, xl, xr, N_);
    gat_fused_kernel<<<2048, 256, 0, stream>>>(
        csr_src, csr_eid, row_ptr, edge_attr, xl, xr, We + (size_t)l * 1024,
        att + l * 64, conv_bias + l * 64, bn_gamma + l * 64, bn_beta + l * 64,
        bn_mean + l * 64, bn_var + l * 64, h, N_);
  }

  hipMemsetAsync(d_out, 0, (size_t)G_ * 128 * 4, stream);
  hipMemsetAsync(counts, 0, (size_t)G_ * 4, stream);
  counts_kernel<<<(N_ + 255) / 256, 256, 0, stream>>>(batch, counts, N_);
  lin_pool_kernel<<<(N_ + 63) / 64, 256, 0, stream>>>(h, lin_W, lin_b, batch,
                                                      (float*)d_out, N_);
  normalize_kernel<<<(G_ * 128 + 255) / 256, 256, 0, stream>>>(
      (float*)d_out, counts, G_ * 128);
}